// Round 2
// baseline (692.896 us; speedup 1.0000x reference)
//
#include <hip/hip_runtime.h>
#include <hip/hip_bf16.h>

typedef __hip_bfloat16 bf16;
typedef __attribute__((ext_vector_type(8))) short short8;
typedef __attribute__((ext_vector_type(4))) short short4_t;
typedef __attribute__((ext_vector_type(4))) float f32x4;

#define MFMA16(a, b, c) __builtin_amdgcn_mfma_f32_16x16x32_bf16(a, b, c, 0, 0, 0)

static constexpr int B_ = 4, S_ = 2048, D_ = 1024;
static constexpr int M_ = B_ * S_;  // 8192 rows for all GEMMs

__device__ __forceinline__ short4_t cvt4(const float4 v) {
  short4_t r;
  r[0] = (short)__bfloat16_as_ushort(__float2bfloat16(v.x));
  r[1] = (short)__bfloat16_as_ushort(__float2bfloat16(v.y));
  r[2] = (short)__bfloat16_as_ushort(__float2bfloat16(v.z));
  r[3] = (short)__bfloat16_as_ushort(__float2bfloat16(v.w));
  return r;
}

// C[m,n] = sum_k A[m,k] * W[n,k]
// A: [8192,1024] K-contig (f32 or bf16). W: [1024,1024] K-contig f32.
// MODE 0: C (float) row-major [M][1024]
// MODE 1: C (bf16) -> [B][H][S][64]   (Q/K head-split)
// MODE 2: C (bf16) -> [B][H][64][S]   (V transposed for PV MFMA B-operand)
template <int MODE, class TA, class TC>
__global__ __launch_bounds__(256) void gemm_bt(const TA* __restrict__ A,
                                               const float* __restrict__ W,
                                               TC* __restrict__ C, float scale) {
  __shared__ __align__(16) bf16 lA[128 * 32];
  __shared__ __align__(16) bf16 lB[128 * 32];
  const int tid = threadIdx.x;
  const int lane = tid & 63;
  const int w = tid >> 6;
  const int wr = w >> 1, wc = w & 1;  // 2x2 waves, 64x64 each
  const int m0 = blockIdx.x * 128;
  const int n0 = blockIdx.y * 128;
  const int l15 = lane & 15, lg = lane >> 4;

  f32x4 zero = {0.f, 0.f, 0.f, 0.f};
  f32x4 acc[4][4];
#pragma unroll
  for (int i = 0; i < 4; i++)
#pragma unroll
    for (int j = 0; j < 4; j++) acc[i][j] = zero;

  for (int kt = 0; kt < 32; ++kt) {
    const int k0 = kt * 32;
    // stage A-tile and W-tile (f32 -> bf16 convert in regs, bf16 pass-through)
#pragma unroll
    for (int j = 0; j < 4; ++j) {
      int e4 = j * 256 + tid;            // 4-element chunk id, 1024 chunks/tile
      int row = e4 >> 3, col = (e4 & 7) * 4;
      short4_t av;
      if constexpr (sizeof(TA) == 4) {
        av = cvt4(*(const float4*)&A[(size_t)(m0 + row) * 1024 + k0 + col]);
      } else {
        av = *(const short4_t*)&A[(size_t)(m0 + row) * 1024 + k0 + col];
      }
      *(short4_t*)&lA[row * 32 + col] = av;
      short4_t wv = cvt4(*(const float4*)&W[(size_t)(n0 + row) * 1024 + k0 + col]);
      *(short4_t*)&lB[row * 32 + col] = wv;
    }
    __syncthreads();

    short8 af[4], bfr[4];
#pragma unroll
    for (int mi = 0; mi < 4; mi++)
      af[mi] = *(const short8*)&lA[(wr * 64 + mi * 16 + l15) * 32 + lg * 8];
#pragma unroll
    for (int ni = 0; ni < 4; ni++)
      bfr[ni] = *(const short8*)&lB[(wc * 64 + ni * 16 + l15) * 32 + lg * 8];
#pragma unroll
    for (int mi = 0; mi < 4; mi++)
#pragma unroll
      for (int ni = 0; ni < 4; ni++) acc[mi][ni] = MFMA16(af[mi], bfr[ni], acc[mi][ni]);
    __syncthreads();
  }

  // C/D layout: col = lane&15, row = (lane>>4)*4 + r
#pragma unroll
  for (int mi = 0; mi < 4; mi++)
#pragma unroll
    for (int ni = 0; ni < 4; ni++)
#pragma unroll
      for (int r = 0; r < 4; r++) {
        int m = m0 + wr * 64 + mi * 16 + lg * 4 + r;
        int n = n0 + wc * 64 + ni * 16 + l15;
        float v = acc[mi][ni][r] * scale;
        size_t idx;
        if constexpr (MODE == 0) {
          idx = (size_t)m * 1024 + n;
        } else {
          int b = m >> 11, s = m & 2047, h = n >> 6, dh = n & 63;
          if constexpr (MODE == 1)
            idx = ((size_t)((b << 4) + h) * 2048 + s) * 64 + dh;
          else
            idx = ((size_t)((b << 4) + h) * 64 + dh) * 2048 + s;
        }
        if constexpr (sizeof(TC) == 4)
          C[idx] = v;
        else
          C[idx] = __float2bfloat16(v);
      }
}

// Flash attention, causal. One wave per 16 Q rows; KV chunks of 32.
// Q pre-scaled by 1/8 in projection epilogue. All operands bf16 (ws buffers).
__global__ __launch_bounds__(256) void attn_fwd(const bf16* __restrict__ Q,
                                                const bf16* __restrict__ K,
                                                const bf16* __restrict__ Vt,
                                                bf16* __restrict__ O) {
  __shared__ __align__(16) bf16 P[4][16 * 32];  // per-wave P tile
  const int tid = threadIdx.x, lane = tid & 63, w = tid >> 6;
  const int bh = blockIdx.x >> 5;               // [0,64): b*16+h
  const int q0 = (blockIdx.x & 31) * 64 + w * 16;
  const bf16* Qb = Q + (size_t)bh * S_ * 64;
  const bf16* Kb = K + (size_t)bh * S_ * 64;
  const bf16* Vb = Vt + (size_t)bh * 64 * S_;
  bf16* Pw = P[w];
  const int l15 = lane & 15, lg = lane >> 4;

  short8 qf[2];
#pragma unroll
  for (int kd = 0; kd < 2; kd++)
    qf[kd] = *(const short8*)&Qb[(size_t)(q0 + l15) * 64 + kd * 32 + lg * 8];

  f32x4 zero = {0.f, 0.f, 0.f, 0.f};
  f32x4 acc[4];
  float mr[4], lr[4];
#pragma unroll
  for (int i = 0; i < 4; i++) { acc[i] = zero; mr[i] = -1e9f; lr[i] = 0.f; }

  const int cmax = (q0 + 15) >> 5;
  for (int c = 0; c <= cmax; ++c) {
    const int c0 = c << 5;
    f32x4 sc[2];
    sc[0] = zero; sc[1] = zero;
#pragma unroll
    for (int ch = 0; ch < 2; ch++)
#pragma unroll
      for (int kd = 0; kd < 2; kd++) {
        short8 kf = *(const short8*)&Kb[(size_t)(c0 + ch * 16 + l15) * 64 + kd * 32 + lg * 8];
        sc[ch] = MFMA16(qf[kd], kf, sc[ch]);
      }
    if (c == cmax) {  // only the diagonal chunk needs masking
#pragma unroll
      for (int ch = 0; ch < 2; ch++)
#pragma unroll
        for (int r = 0; r < 4; r++) {
          int kv = c0 + ch * 16 + l15, q = q0 + lg * 4 + r;
          if (kv > q) sc[ch][r] = -1e9f;
        }
    }
#pragma unroll
    for (int r = 0; r < 4; r++) {
      float v = fmaxf(sc[0][r], sc[1][r]);
#pragma unroll
      for (int mk = 1; mk < 16; mk <<= 1) v = fmaxf(v, __shfl_xor(v, mk));
      float mn = fmaxf(mr[r], v);
      float corr = __expf(mr[r] - mn);
      float p0 = __expf(sc[0][r] - mn);
      float p1 = __expf(sc[1][r] - mn);
      float ps = p0 + p1;
#pragma unroll
      for (int mk = 1; mk < 16; mk <<= 1) ps += __shfl_xor(ps, mk);
      lr[r] = lr[r] * corr + ps;
      mr[r] = mn;
#pragma unroll
      for (int ni = 0; ni < 4; ni++) acc[ni][r] *= corr;
      Pw[(lg * 4 + r) * 32 + l15] = __float2bfloat16(p0);
      Pw[(lg * 4 + r) * 32 + 16 + l15] = __float2bfloat16(p1);
    }
    // PV: A = P[16 q][32 kv], B = Vt[dh][kv] (contiguous along kv)
    short8 pf = *(const short8*)&Pw[l15 * 32 + lg * 8];
#pragma unroll
    for (int ni = 0; ni < 4; ni++) {
      short8 vf = *(const short8*)&Vb[(size_t)(ni * 16 + l15) * 2048 + c0 + lg * 8];
      acc[ni] = MFMA16(pf, vf, acc[ni]);
    }
  }

  const int b = bh >> 4, h = bh & 15;
#pragma unroll
  for (int ni = 0; ni < 4; ni++)
#pragma unroll
    for (int r = 0; r < 4; r++) {
      int q = q0 + lg * 4 + r;
      size_t idx = ((size_t)(b * 2048 + q)) * 1024 + h * 64 + ni * 16 + l15;
      O[idx] = __float2bfloat16(acc[ni][r] / lr[r]);
    }
}

extern "C" void kernel_launch(void* const* d_in, const int* in_sizes, int n_in,
                              void* d_out, int out_size, void* d_ws, size_t ws_size,
                              hipStream_t stream) {
  const float* x = (const float*)d_in[0];
  const float* wq = (const float*)d_in[1];
  const float* wk = (const float*)d_in[2];
  const float* wv = (const float*)d_in[3];
  const float* wo = (const float*)d_in[4];
  float* out = (float*)d_out;

  const size_t SZ = (size_t)M_ * D_;  // 8.39M elems bf16 = 16.78 MB each
  bf16* Qw = (bf16*)d_ws;             // [B][H][S][64], pre-scaled by 0.125
  bf16* Kw = Qw + SZ;                 // [B][H][S][64]
  bf16* Vw = Kw + SZ;                 // [B][H][64][S]  (transposed)
  bf16* AO = Vw + SZ;                 // [B][S][1024]   attention output (bf16)
  // total ws use: 4 * 16.78 MB = 67 MB

  dim3 grid(64, 8), blk(256);
  hipLaunchKernelGGL((gemm_bt<1, float, bf16>), grid, blk, 0, stream, x, wq, Qw, 0.125f);
  hipLaunchKernelGGL((gemm_bt<1, float, bf16>), grid, blk, 0, stream, x, wk, Kw, 1.0f);
  hipLaunchKernelGGL((gemm_bt<2, float, bf16>), grid, blk, 0, stream, x, wv, Vw, 1.0f);
  hipLaunchKernelGGL(attn_fwd, dim3(2048), blk, 0, stream, Qw, Kw, Vw, AO);
  hipLaunchKernelGGL((gemm_bt<0, bf16, float>), grid, blk, 0, stream, AO, wo, out, 1.0f);
}

// Round 3
// 389.296 us; speedup vs baseline: 1.7799x; 1.7799x over previous
//
#include <hip/hip_runtime.h>
#include <hip/hip_bf16.h>

typedef __hip_bfloat16 bf16;
typedef __attribute__((ext_vector_type(8))) short short8;
typedef __attribute__((ext_vector_type(4))) short short4_t;
typedef __attribute__((ext_vector_type(4))) float f32x4;

#define MFMA16(a, b, c) __builtin_amdgcn_mfma_f32_16x16x32_bf16(a, b, c, 0, 0, 0)

static constexpr int S_ = 2048, D_ = 1024, M_ = 8192;

__device__ __forceinline__ void gload16(void* lds, const void* g) {
  __builtin_amdgcn_global_load_lds((const __attribute__((address_space(1))) void*)g,
                                   (__attribute__((address_space(3))) void*)lds, 16, 0, 0);
}

__device__ __forceinline__ short4_t cvt4(const float4 v) {
  short4_t r;
  r[0] = (short)__bfloat16_as_ushort(__float2bfloat16(v.x));
  r[1] = (short)__bfloat16_as_ushort(__float2bfloat16(v.y));
  r[2] = (short)__bfloat16_as_ushort(__float2bfloat16(v.z));
  r[3] = (short)__bfloat16_as_ushort(__float2bfloat16(v.w));
  return r;
}

// f32 -> bf16 bulk convert (x only; weights converted in-GEMM)
__global__ __launch_bounds__(256) void cvt_f32_bf16(const float* __restrict__ in,
                                                    bf16* __restrict__ out, int n4) {
  int stride = gridDim.x * 256;
  for (int i = blockIdx.x * 256 + threadIdx.x; i < n4; i += stride) {
    float4 v = ((const float4*)in)[i];
    *(short4_t*)&out[(size_t)i * 4] = cvt4(v);
  }
}

// C[m,n] = sum_k A[m,k] * W[n,k].  A bf16 (gload16-staged), W f32 (reg-cvt-staged).
// MODE 0: C (f32) row-major [M][1024]
// MODE 1: C (bf16) -> [B][H][S][64]
// MODE 2: C (bf16) -> [B][H][64][S]  (V transposed)
template <int MODE, class TC>
__global__ __launch_bounds__(256) void gemm_bt(const bf16* __restrict__ A,
                                               const float* __restrict__ W,
                                               TC* __restrict__ C, float scale) {
  __shared__ __align__(16) bf16 lA[128 * 32];
  __shared__ __align__(16) bf16 lB[128 * 32];
  const int tid = threadIdx.x, lane = tid & 63, w = tid >> 6;
  const int wr = w >> 1, wc = w & 1;
  const int m0 = blockIdx.x * 128, n0 = blockIdx.y * 128;
  const int l15 = lane & 15, lg = lane >> 4;

  f32x4 zero = {0.f, 0.f, 0.f, 0.f};
  f32x4 acc[4][4];
#pragma unroll
  for (int i = 0; i < 4; i++)
#pragma unroll
    for (int j = 0; j < 4; j++) acc[i][j] = zero;

  for (int kt = 0; kt < 32; ++kt) {
    const int k0 = kt * 32;
#pragma unroll
    for (int i = 0; i < 2; ++i) {  // A tile: 8KB via global_load_lds
      int c = i * 256 + tid;
      int row = c >> 2, col = (c & 3) * 8;
      gload16(&lA[c * 8], &A[(size_t)(m0 + row) * 1024 + k0 + col]);
    }
#pragma unroll
    for (int j = 0; j < 4; ++j) {  // W tile: f32 -> bf16 in regs
      int e4 = j * 256 + tid;
      int row = e4 >> 3, col = (e4 & 7) * 4;
      *(short4_t*)&lB[row * 32 + col] = cvt4(*(const float4*)&W[(size_t)(n0 + row) * 1024 + k0 + col]);
    }
    __syncthreads();

    short8 af[4], bfr[4];
#pragma unroll
    for (int mi = 0; mi < 4; mi++)
      af[mi] = *(const short8*)&lA[(wr * 64 + mi * 16 + l15) * 32 + lg * 8];
#pragma unroll
    for (int ni = 0; ni < 4; ni++)
      bfr[ni] = *(const short8*)&lB[(wc * 64 + ni * 16 + l15) * 32 + lg * 8];
#pragma unroll
    for (int mi = 0; mi < 4; mi++)
#pragma unroll
      for (int ni = 0; ni < 4; ni++) acc[mi][ni] = MFMA16(af[mi], bfr[ni], acc[mi][ni]);
    __syncthreads();
  }

#pragma unroll
  for (int mi = 0; mi < 4; mi++)
#pragma unroll
    for (int ni = 0; ni < 4; ni++)
#pragma unroll
      for (int r = 0; r < 4; r++) {
        int m = m0 + wr * 64 + mi * 16 + lg * 4 + r;
        int n = n0 + wc * 64 + ni * 16 + l15;
        float v = acc[mi][ni][r] * scale;
        size_t idx;
        if constexpr (MODE == 0) {
          idx = (size_t)m * 1024 + n;
        } else {
          int b = m >> 11, s = m & 2047, h = n >> 6, dh = n & 63;
          if constexpr (MODE == 1)
            idx = ((size_t)((b << 4) + h) * 2048 + s) * 64 + dh;
          else
            idx = ((size_t)((b << 4) + h) * 64 + dh) * 2048 + s;
        }
        if constexpr (sizeof(TC) == 4)
          C[idx] = v;
        else
          C[idx] = __float2bfloat16(v);
      }
}

// Flash attention, causal. 4 waves/block, 32 Q rows/wave (QBLK=128), KVBLK=64.
// K/V staged in LDS (global_load_lds, double-buffered, counted vmcnt), XOR-swizzled.
__global__ __launch_bounds__(256, 3) void attn_fwd(const bf16* __restrict__ Q,
                                                   const bf16* __restrict__ K,
                                                   const bf16* __restrict__ Vt,
                                                   bf16* __restrict__ O) {
  __shared__ __align__(16) bf16 lK[2][64 * 64];
  __shared__ __align__(16) bf16 lV[2][64 * 64];
  __shared__ __align__(16) bf16 lP[4][32 * 64];
  const int tid = threadIdx.x, lane = tid & 63, w = tid >> 6;
  const int l15 = lane & 15, lg = lane >> 4;
  const int bh = blockIdx.x, qb = blockIdx.y;
  const int q0 = qb * 128 + w * 32;
  const bf16* Qb = Q + (size_t)bh * S_ * 64;
  const bf16* Kb = K + (size_t)bh * S_ * 64;
  const bf16* Vb = Vt + (size_t)bh * 64 * S_;
  bf16* Pw = lP[w];

  short8 qf[2][2];
#pragma unroll
  for (int mi = 0; mi < 2; mi++)
#pragma unroll
    for (int kd = 0; kd < 2; kd++)
      qf[mi][kd] = *(const short8*)&Qb[(size_t)(q0 + mi * 16 + l15) * 64 + kd * 32 + lg * 8];

  f32x4 zero = {0.f, 0.f, 0.f, 0.f};
  f32x4 acc[2][4];
  float mr[2][4], lr[2][4];
#pragma unroll
  for (int mi = 0; mi < 2; mi++)
#pragma unroll
    for (int r = 0; r < 4; r++) { acc[mi][r] = zero; mr[mi][r] = -1e9f; lr[mi][r] = 0.f; }
#pragma unroll
  for (int mi = 0; mi < 2; mi++)
#pragma unroll
    for (int ni = 0; ni < 4; ni++) acc[mi][ni] = zero;

  const int nch = (qb + 1) * 2;

  // stage chunk c: K tile [64 kv][64 d], V tile [64 dh][64 kv]; linear LDS dest,
  // inverse-XOR-swizzled global source (rule #21): LDS[row][cb] = global[row][cb ^ ((row&7)<<4)]
#define STAGE(buf, c)                                                                   \
  {                                                                                     \
    _Pragma("unroll") for (int i = 0; i < 2; ++i) {                                     \
      int t2 = i * 256 + tid;                                                           \
      int row = t2 >> 3;                                                                \
      int cb = ((t2 & 7) * 16) ^ ((row & 7) << 4);                                      \
      gload16((char*)lK[buf] + t2 * 16, (const char*)Kb + (size_t)((c) * 64 + row) * 128 + cb); \
      gload16((char*)lV[buf] + t2 * 16, (const char*)Vb + (size_t)row * 4096 + (size_t)(c) * 128 + cb); \
    }                                                                                   \
  }

  STAGE(0, 0);
  int cur = 0;
  for (int c = 0; c < nch; ++c) {
    __builtin_amdgcn_s_barrier();  // all waves done reading the buffer we overwrite next
    if (c + 1 < nch) {
      STAGE(cur ^ 1, c + 1);
      asm volatile("s_waitcnt vmcnt(4)" ::: "memory");  // chunk c's 4 loads done; next 4 in flight
    } else {
      asm volatile("s_waitcnt vmcnt(0)" ::: "memory");
    }
    __builtin_amdgcn_s_barrier();  // buf[cur] complete for all threads

    // QK^T: A = Q frags, B = K rows from swizzled LDS
    f32x4 sc[2][4];
#pragma unroll
    for (int mi = 0; mi < 2; mi++)
#pragma unroll
      for (int ch = 0; ch < 4; ch++) sc[mi][ch] = zero;
    const char* Kc = (const char*)lK[cur];
#pragma unroll
    for (int kd = 0; kd < 2; ++kd)
#pragma unroll
      for (int ch = 0; ch < 4; ++ch) {
        short8 kf = *(const short8*)(Kc + (ch * 16 + l15) * 128 + (((kd * 64 + lg * 16)) ^ ((l15 & 7) << 4)));
        sc[0][ch] = MFMA16(qf[0][kd], kf, sc[0][ch]);
        sc[1][ch] = MFMA16(qf[1][kd], kf, sc[1][ch]);
      }

    if (c * 64 + 63 > q0) {  // diagonal / above-diagonal chunk: causal mask
#pragma unroll
      for (int mi = 0; mi < 2; mi++)
#pragma unroll
        for (int ch = 0; ch < 4; ch++)
#pragma unroll
          for (int r = 0; r < 4; r++) {
            int kv = c * 64 + ch * 16 + l15;
            int q = q0 + mi * 16 + lg * 4 + r;
            if (kv > q) sc[mi][ch][r] = -1e9f;
          }
    }

    // online softmax (16-lane reduce within lg group) + swizzled P write
#pragma unroll
    for (int mi = 0; mi < 2; mi++)
#pragma unroll
      for (int r = 0; r < 4; r++) {
        float v = fmaxf(fmaxf(sc[mi][0][r], sc[mi][1][r]), fmaxf(sc[mi][2][r], sc[mi][3][r]));
#pragma unroll
        for (int mk = 1; mk < 16; mk <<= 1) v = fmaxf(v, __shfl_xor(v, mk));
        float mn = fmaxf(mr[mi][r], v);
        float corr = __expf(mr[mi][r] - mn);
        float p[4], ps = 0.f;
#pragma unroll
        for (int ch = 0; ch < 4; ch++) { p[ch] = __expf(sc[mi][ch][r] - mn); ps += p[ch]; }
#pragma unroll
        for (int mk = 1; mk < 16; mk <<= 1) ps += __shfl_xor(ps, mk);
        lr[mi][r] = lr[mi][r] * corr + ps;
        mr[mi][r] = mn;
#pragma unroll
        for (int ni = 0; ni < 4; ni++) acc[mi][ni][r] *= corr;
        int row = mi * 16 + lg * 4 + r;
        char* Pb = (char*)Pw + row * 128;
        int sw = (row & 7) << 4;
#pragma unroll
        for (int ch = 0; ch < 4; ch++)
          *(bf16*)(Pb + (((ch * 16 + l15) * 2) ^ sw)) = __float2bfloat16(p[ch]);
      }

    // PV: A = P (swizzled LDS), B = V rows (swizzled LDS)
    const char* Vc = (const char*)lV[cur];
#pragma unroll
    for (int kd = 0; kd < 2; ++kd) {
      short8 pf[2];
#pragma unroll
      for (int mi = 0; mi < 2; mi++)
        pf[mi] = *(const short8*)((const char*)Pw + (mi * 16 + l15) * 128 + ((kd * 64 + lg * 16) ^ ((l15 & 7) << 4)));
#pragma unroll
      for (int ni = 0; ni < 4; ++ni) {
        short8 vf = *(const short8*)(Vc + (ni * 16 + l15) * 128 + ((kd * 64 + lg * 16) ^ ((l15 & 7) << 4)));
        acc[0][ni] = MFMA16(pf[0], vf, acc[0][ni]);
        acc[1][ni] = MFMA16(pf[1], vf, acc[1][ni]);
      }
    }
    cur ^= 1;
  }
#undef STAGE

  const int b = bh >> 4, h = bh & 15;
#pragma unroll
  for (int mi = 0; mi < 2; mi++)
#pragma unroll
    for (int ni = 0; ni < 4; ni++)
#pragma unroll
      for (int r = 0; r < 4; r++) {
        int q = q0 + mi * 16 + lg * 4 + r;
        size_t idx = ((size_t)(b * 2048 + q)) * 1024 + h * 64 + ni * 16 + l15;
        O[idx] = __float2bfloat16(acc[mi][ni][r] / lr[mi][r]);
      }
}

extern "C" void kernel_launch(void* const* d_in, const int* in_sizes, int n_in,
                              void* d_out, int out_size, void* d_ws, size_t ws_size,
                              hipStream_t stream) {
  const float* x = (const float*)d_in[0];
  const float* wq = (const float*)d_in[1];
  const float* wk = (const float*)d_in[2];
  const float* wv = (const float*)d_in[3];
  const float* wo = (const float*)d_in[4];
  float* out = (float*)d_out;

  const size_t SZ = (size_t)M_ * D_;  // 8.39M elems
  bf16* xb = (bf16*)d_ws;             // [M][1024] bf16 x; reused as AO after attn
  bf16* Qw = xb + SZ;                 // [B][H][S][64], pre-scaled by 0.125
  bf16* Kw = Qw + SZ;                 // [B][H][S][64]
  bf16* Vw = Kw + SZ;                 // [B][H][64][S]
  bf16* AO = xb;                      // xb dead after V-GEMM
  // ws use: 4 * 16.78 MB = 67 MB (same as round 1)

  dim3 blk(256);
  hipLaunchKernelGGL(cvt_f32_bf16, dim3(1024), blk, 0, stream, x, xb, (int)(SZ / 4));
  dim3 grid(64, 8);
  hipLaunchKernelGGL((gemm_bt<1, bf16>), grid, blk, 0, stream, xb, wq, Qw, 0.125f);
  hipLaunchKernelGGL((gemm_bt<1, bf16>), grid, blk, 0, stream, xb, wk, Kw, 1.0f);
  hipLaunchKernelGGL((gemm_bt<2, bf16>), grid, blk, 0, stream, xb, wv, Vw, 1.0f);
  hipLaunchKernelGGL(attn_fwd, dim3(64, 16), blk, 0, stream, Qw, Kw, Vw, AO);
  hipLaunchKernelGGL((gemm_bt<0, float>), grid, blk, 0, stream, AO, wo, out, 1.0f);
}

// Round 4
// 277.361 us; speedup vs baseline: 2.4982x; 1.4036x over previous
//
#include <hip/hip_runtime.h>
#include <hip/hip_bf16.h>

typedef __hip_bfloat16 bf16;
typedef __attribute__((ext_vector_type(8))) short short8;
typedef __attribute__((ext_vector_type(4))) short short4_t;
typedef __attribute__((ext_vector_type(4))) float f32x4;
typedef unsigned int u32;

#define MFMA16(a, b, c) __builtin_amdgcn_mfma_f32_16x16x32_bf16(a, b, c, 0, 0, 0)

static constexpr int S_ = 2048, D_ = 1024, M_ = 8192;

__device__ __forceinline__ void gload16(void* lds, const void* g) {
  __builtin_amdgcn_global_load_lds((const __attribute__((address_space(1))) void*)g,
                                   (__attribute__((address_space(3))) void*)lds, 16, 0, 0);
}

__device__ __forceinline__ short4_t cvt4(const float4 v) {
  short4_t r;
  r[0] = (short)__bfloat16_as_ushort(__float2bfloat16(v.x));
  r[1] = (short)__bfloat16_as_ushort(__float2bfloat16(v.y));
  r[2] = (short)__bfloat16_as_ushort(__float2bfloat16(v.z));
  r[3] = (short)__bfloat16_as_ushort(__float2bfloat16(v.w));
  return r;
}

__device__ __forceinline__ u32 pk2(float a, float b) {
  return (u32)__bfloat16_as_ushort(__float2bfloat16(a)) |
         ((u32)__bfloat16_as_ushort(__float2bfloat16(b)) << 16);
}

__global__ __launch_bounds__(256) void cvt_f32_bf16(const float* __restrict__ in,
                                                    bf16* __restrict__ out, int n4) {
  int stride = gridDim.x * 256;
  for (int i = blockIdx.x * 256 + threadIdx.x; i < n4; i += stride) {
    float4 v = ((const float4*)in)[i];
    *(short4_t*)&out[(size_t)i * 4] = cvt4(v);
  }
}

// C[m,n] = sum_k A[m,k]*W[n,k]; A,W both bf16, both gload16-staged (m97 structure).
// MODE 0: C f32 row-major. MODE 1: C bf16 [B][H][S][64]. MODE 2: C bf16 [B][H][64][S].
template <int MODE, class TC>
__global__ __launch_bounds__(256) void gemm_bt(const bf16* __restrict__ A,
                                               const bf16* __restrict__ W,
                                               TC* __restrict__ C, float scale) {
  __shared__ __align__(16) bf16 lA[128 * 32];
  __shared__ __align__(16) bf16 lB[128 * 32];
  const int tid = threadIdx.x, lane = tid & 63, w = tid >> 6;
  const int wr = w >> 1, wc = w & 1;
  const int m0 = blockIdx.x * 128, n0 = blockIdx.y * 128;
  const int l15 = lane & 15, lg = lane >> 4;

  f32x4 zero = {0.f, 0.f, 0.f, 0.f};
  f32x4 acc[4][4];
#pragma unroll
  for (int i = 0; i < 4; i++)
#pragma unroll
    for (int j = 0; j < 4; j++) acc[i][j] = zero;

  for (int kt = 0; kt < 32; ++kt) {
    const int k0 = kt * 32;
#pragma unroll
    for (int i = 0; i < 2; ++i) {
      int c = i * 256 + tid;
      int row = c >> 2, col = (c & 3) * 8;
      gload16(&lA[c * 8], &A[(size_t)(m0 + row) * 1024 + k0 + col]);
      gload16(&lB[c * 8], &W[(size_t)(n0 + row) * 1024 + k0 + col]);
    }
    __syncthreads();

    short8 af[4], bfr[4];
#pragma unroll
    for (int mi = 0; mi < 4; mi++)
      af[mi] = *(const short8*)&lA[(wr * 64 + mi * 16 + l15) * 32 + lg * 8];
#pragma unroll
    for (int ni = 0; ni < 4; ni++)
      bfr[ni] = *(const short8*)&lB[(wc * 64 + ni * 16 + l15) * 32 + lg * 8];
#pragma unroll
    for (int mi = 0; mi < 4; mi++)
#pragma unroll
      for (int ni = 0; ni < 4; ni++) acc[mi][ni] = MFMA16(af[mi], bfr[ni], acc[mi][ni]);
    __syncthreads();
  }

#pragma unroll
  for (int mi = 0; mi < 4; mi++)
#pragma unroll
    for (int ni = 0; ni < 4; ni++)
#pragma unroll
      for (int r = 0; r < 4; r++) {
        int m = m0 + wr * 64 + mi * 16 + lg * 4 + r;
        int n = n0 + wc * 64 + ni * 16 + l15;
        float v = acc[mi][ni][r] * scale;
        size_t idx;
        if constexpr (MODE == 0) {
          idx = (size_t)m * 1024 + n;
        } else {
          int b = m >> 11, s = m & 2047, h = n >> 6, dh = n & 63;
          if constexpr (MODE == 1)
            idx = ((size_t)((b << 4) + h) * 2048 + s) * 64 + dh;
          else
            idx = ((size_t)((b << 4) + h) * 64 + dh) * 2048 + s;
        }
        if constexpr (sizeof(TC) == 4)
          C[idx] = v;
        else
          C[idx] = __float2bfloat16(v);
      }
}

// Flash attention, causal. 4 waves, 32 Q rows/wave, KVBLK=64, dbuf LDS (counted vmcnt).
// Swapped QK^T: sc[mi][ch][r] = S[kv=c0+ch*16+lg*4+r][q=q0+mi*16+l15] -> lane-local softmax.
__global__ __launch_bounds__(256, 3) void attn_fwd(const bf16* __restrict__ Q,
                                                   const bf16* __restrict__ K,
                                                   const bf16* __restrict__ Vt,
                                                   bf16* __restrict__ O) {
  __shared__ __align__(16) bf16 lK[2][64 * 64];
  __shared__ __align__(16) bf16 lV[2][64 * 64];
  __shared__ __align__(16) bf16 lP[4][32 * 64];
  const int tid = threadIdx.x, lane = tid & 63, w = tid >> 6;
  const int l15 = lane & 15, lg = lane >> 4;
  const int bh = blockIdx.x;
  const int qb = 15 - blockIdx.y;  // reversed: heavy blocks scheduled first (LPT)
  const int q0 = qb * 128 + w * 32;
  const bf16* Qb = Q + (size_t)bh * S_ * 64;
  const bf16* Kb = K + (size_t)bh * S_ * 64;
  const bf16* Vb = Vt + (size_t)bh * 64 * S_;
  bf16* Pw = lP[w];

  short8 qf[2][2];
#pragma unroll
  for (int mi = 0; mi < 2; mi++)
#pragma unroll
    for (int kd = 0; kd < 2; kd++)
      qf[mi][kd] = *(const short8*)&Qb[(size_t)(q0 + mi * 16 + l15) * 64 + kd * 32 + lg * 8];

  f32x4 zero = {0.f, 0.f, 0.f, 0.f};
  f32x4 acc[2][4];
  float mr[2], lr[2];
#pragma unroll
  for (int mi = 0; mi < 2; mi++) {
    mr[mi] = -1e9f;
    lr[mi] = 0.f;
#pragma unroll
    for (int ni = 0; ni < 4; ni++) acc[mi][ni] = zero;
  }

  const int nch = (qb + 1) * 2;

#define STAGE(buf, c)                                                                   \
  {                                                                                     \
    _Pragma("unroll") for (int i = 0; i < 2; ++i) {                                     \
      int t2 = i * 256 + tid;                                                           \
      int row = t2 >> 3;                                                                \
      int cb = ((t2 & 7) * 16) ^ ((row & 7) << 4);                                      \
      gload16((char*)lK[buf] + t2 * 16, (const char*)Kb + (size_t)((c) * 64 + row) * 128 + cb); \
      gload16((char*)lV[buf] + t2 * 16, (const char*)Vb + (size_t)row * 4096 + (size_t)(c) * 128 + cb); \
    }                                                                                   \
  }

  STAGE(0, 0);
  int cur = 0;
  for (int c = 0; c < nch; ++c) {
    __builtin_amdgcn_s_barrier();
    if (c + 1 < nch) {
      STAGE(cur ^ 1, c + 1);
      asm volatile("s_waitcnt vmcnt(4)" ::: "memory");
    } else {
      asm volatile("s_waitcnt vmcnt(0)" ::: "memory");
    }
    __builtin_amdgcn_s_barrier();

    if (c * 64 <= q0 + 31) {  // skip compute for fully-masked chunks (barriers still hit)
      const int c0 = c * 64;
      f32x4 sc[2][4];
#pragma unroll
      for (int mi = 0; mi < 2; mi++)
#pragma unroll
        for (int ch = 0; ch < 4; ch++) sc[mi][ch] = zero;
      const char* Kc = (const char*)lK[cur];
      __builtin_amdgcn_s_setprio(1);
#pragma unroll
      for (int kd = 0; kd < 2; ++kd)
#pragma unroll
        for (int ch = 0; ch < 4; ++ch) {
          short8 kf = *(const short8*)(Kc + (ch * 16 + l15) * 128 + ((kd * 64 + lg * 16) ^ ((l15 & 7) << 4)));
          sc[0][ch] = MFMA16(kf, qf[0][kd], sc[0][ch]);  // swapped: D[kv][q]
          sc[1][ch] = MFMA16(kf, qf[1][kd], sc[1][ch]);
        }
      __builtin_amdgcn_s_setprio(0);

      if (c0 + 63 > q0) {  // causal mask on diagonal chunks
#pragma unroll
        for (int mi = 0; mi < 2; mi++) {
          int q = q0 + mi * 16 + l15;
#pragma unroll
          for (int ch = 0; ch < 4; ch++)
#pragma unroll
            for (int r = 0; r < 4; r++) {
              int kv = c0 + ch * 16 + lg * 4 + r;
              if (kv > q) sc[mi][ch][r] = -1e9f;
            }
        }
      }

      // lane-local online softmax (q = l15 per lane)
#pragma unroll
      for (int mi = 0; mi < 2; mi++) {
        float v01 = fmaxf(fmaxf(sc[mi][0][0], sc[mi][0][1]), fmaxf(sc[mi][0][2], sc[mi][0][3]));
        float v1 = fmaxf(fmaxf(sc[mi][1][0], sc[mi][1][1]), fmaxf(sc[mi][1][2], sc[mi][1][3]));
        float v2 = fmaxf(fmaxf(sc[mi][2][0], sc[mi][2][1]), fmaxf(sc[mi][2][2], sc[mi][2][3]));
        float v3 = fmaxf(fmaxf(sc[mi][3][0], sc[mi][3][1]), fmaxf(sc[mi][3][2], sc[mi][3][3]));
        float vmax = fmaxf(fmaxf(v01, v1), fmaxf(v2, v3));
        vmax = fmaxf(vmax, __shfl_xor(vmax, 16));
        vmax = fmaxf(vmax, __shfl_xor(vmax, 32));
        float mn = fmaxf(mr[mi], vmax);
        float corr = __expf(mr[mi] - mn);
        mr[mi] = mn;
        float ps = 0.f;
#pragma unroll
        for (int ch = 0; ch < 4; ch++)
#pragma unroll
          for (int r = 0; r < 4; r++) {
            float p = __expf(sc[mi][ch][r] - mn);
            sc[mi][ch][r] = p;
            ps += p;
          }
        ps += __shfl_xor(ps, 16);
        ps += __shfl_xor(ps, 32);
        lr[mi] = lr[mi] * corr + ps;
        // broadcast corr to acc-row lanes (acc row q = lg*4+r, corr lives at l15=q)
#pragma unroll
        for (int r = 0; r < 4; r++) {
          float cr = __shfl(corr, (lane & 48) | (((lane >> 4) << 2) + r));
#pragma unroll
          for (int ni = 0; ni < 4; ni++) acc[mi][ni][r] *= cr;
        }
        // packed P write: row = q, 4x ds_write_b64
        int row = mi * 16 + l15;
        char* Pb = (char*)Pw + row * 128;
        int sw = (row & 7) << 4;
#pragma unroll
        for (int ch = 0; ch < 4; ch++) {
          u32 d0 = pk2(sc[mi][ch][0], sc[mi][ch][1]);
          u32 d1 = pk2(sc[mi][ch][2], sc[mi][ch][3]);
          uint2 dd = {d0, d1};
          *(uint2*)(Pb + ((ch * 32 + lg * 8) ^ sw)) = dd;
        }
      }

      asm volatile("s_waitcnt lgkmcnt(0)" ::: "memory");  // P writes -> own reads
      const char* Vc = (const char*)lV[cur];
      __builtin_amdgcn_s_setprio(1);
#pragma unroll
      for (int kd = 0; kd < 2; ++kd) {
        short8 pf[2];
#pragma unroll
        for (int mi = 0; mi < 2; mi++)
          pf[mi] = *(const short8*)((const char*)Pw + (mi * 16 + l15) * 128 +
                                    ((kd * 64 + lg * 16) ^ ((l15 & 7) << 4)));
#pragma unroll
        for (int ni = 0; ni < 4; ++ni) {
          short8 vf = *(const short8*)(Vc + (ni * 16 + l15) * 128 + ((kd * 64 + lg * 16) ^ ((l15 & 7) << 4)));
          acc[0][ni] = MFMA16(pf[0], vf, acc[0][ni]);
          acc[1][ni] = MFMA16(pf[1], vf, acc[1][ni]);
        }
      }
      __builtin_amdgcn_s_setprio(0);
    }
    cur ^= 1;
  }
#undef STAGE

  const int b = bh >> 4, h = bh & 15;
#pragma unroll
  for (int mi = 0; mi < 2; mi++) {
    float lrr[4];
#pragma unroll
    for (int r = 0; r < 4; r++)
      lrr[r] = __shfl(lr[mi], (lane & 48) | (((lane >> 4) << 2) + r));
#pragma unroll
    for (int ni = 0; ni < 4; ni++)
#pragma unroll
      for (int r = 0; r < 4; r++) {
        int q = q0 + mi * 16 + lg * 4 + r;
        size_t idx = ((size_t)(b * 2048 + q)) * 1024 + h * 64 + ni * 16 + l15;
        O[idx] = __float2bfloat16(acc[mi][ni][r] / lrr[r]);
      }
  }
}

extern "C" void kernel_launch(void* const* d_in, const int* in_sizes, int n_in,
                              void* d_out, int out_size, void* d_ws, size_t ws_size,
                              hipStream_t stream) {
  const float* x = (const float*)d_in[0];
  const float* wq = (const float*)d_in[1];
  const float* wk = (const float*)d_in[2];
  const float* wv = (const float*)d_in[3];
  const float* wo = (const float*)d_in[4];
  float* out = (float*)d_out;

  const size_t SZ = (size_t)M_ * D_;   // 8.39M
  const size_t WSZ = (size_t)D_ * D_;  // 1.05M
  bf16* xb = (bf16*)d_ws;              // x bf16; becomes AO after attn
  bf16* Qw = xb + SZ;                  // pre-scaled by 0.125
  bf16* Kw = Qw + SZ;
  bf16* Vw = Kw + SZ;                  // [B][H][64][S] transposed
  bf16* AO = xb;
  // weight bf16 scratch: wq/wk/wv live in d_out (dead until final GEMM); wo overlays Qw
  bf16* wqb = (bf16*)d_out;
  bf16* wkb = wqb + WSZ;
  bf16* wvb = wkb + WSZ;
  bf16* wob = Qw;  // Qw dead after attn

  dim3 blk(256), grid(64, 8);
  hipLaunchKernelGGL(cvt_f32_bf16, dim3(2048), blk, 0, stream, x, xb, (int)(SZ / 4));
  hipLaunchKernelGGL(cvt_f32_bf16, dim3(1024), blk, 0, stream, wq, wqb, (int)(WSZ / 4));
  hipLaunchKernelGGL(cvt_f32_bf16, dim3(1024), blk, 0, stream, wk, wkb, (int)(WSZ / 4));
  hipLaunchKernelGGL(cvt_f32_bf16, dim3(1024), blk, 0, stream, wv, wvb, (int)(WSZ / 4));
  hipLaunchKernelGGL((gemm_bt<1, bf16>), grid, blk, 0, stream, xb, wqb, Qw, 0.125f);
  hipLaunchKernelGGL((gemm_bt<1, bf16>), grid, blk, 0, stream, xb, wkb, Kw, 1.0f);
  hipLaunchKernelGGL((gemm_bt<2, bf16>), grid, blk, 0, stream, xb, wvb, Vw, 1.0f);
  hipLaunchKernelGGL(attn_fwd, dim3(64, 16), blk, 0, stream, Qw, Kw, Vw, AO);
  hipLaunchKernelGGL(cvt_f32_bf16, dim3(1024), blk, 0, stream, wo, wob, (int)(WSZ / 4));
  hipLaunchKernelGGL((gemm_bt<0, float>), grid, blk, 0, stream, AO, wob, out, 1.0f);
}